// Round 2
// baseline (1024.229 us; speedup 1.0000x reference)
//
#include <hip/hip_runtime.h>
#include <stdint.h>
#include <math.h>

#define TOKENS 8192
#define DMODEL 2048
#define HID    8192

typedef __attribute__((ext_vector_type(4))) int v4i;

typedef const __attribute__((address_space(1))) uint32_t gu32;
typedef __attribute__((address_space(3))) uint32_t lu32;

__device__ __forceinline__ void gload16(const void* g, void* l) {
  // async global->LDS DMA, 16B per lane; LDS dest = wave-uniform base + lane*16
  __builtin_amdgcn_global_load_lds((gu32*)g, (lu32*)l, 16, 0, 0);
}

// ---------------- weight absmean: partial |w| sums (fp64) ----------------
__global__ __launch_bounds__(256) void k_abssum(const float* __restrict__ w, long long n4,
                                                double* __restrict__ partial) {
  long long i0 = (long long)blockIdx.x * 256 + threadIdx.x;
  long long stride = (long long)gridDim.x * 256;
  const float4* w4 = (const float4*)w;
  double s = 0.0;
  for (long long i = i0; i < n4; i += stride) {
    float4 v = w4[i];
    s += (double)fabsf(v.x) + (double)fabsf(v.y) + (double)fabsf(v.z) + (double)fabsf(v.w);
  }
  __shared__ double sm[256];
  sm[threadIdx.x] = s;
  __syncthreads();
  for (int off = 128; off > 0; off >>= 1) {
    if ((int)threadIdx.x < off) sm[threadIdx.x] += sm[threadIdx.x + off];
    __syncthreads();
  }
  if (threadIdx.x == 0) partial[blockIdx.x] = sm[0];
}

// ---------------- finalize: s = max(mean|w|, 1e-5) for both weights ----------------
__global__ __launch_bounds__(256) void k_finalize(const double* __restrict__ pg, int ng, double cg,
                                                  const double* __restrict__ po, int no, double co,
                                                  float* __restrict__ scales) {
  __shared__ double sm[256];
  int tid = threadIdx.x;
  double s = 0.0;
  for (int i = tid; i < ng; i += 256) s += pg[i];
  sm[tid] = s; __syncthreads();
  for (int off = 128; off > 0; off >>= 1) { if (tid < off) sm[tid] += sm[tid + off]; __syncthreads(); }
  if (tid == 0) scales[0] = (float)fmax(sm[0] / cg, 1e-5);
  __syncthreads();
  s = 0.0;
  for (int i = tid; i < no; i += 256) s += po[i];
  sm[tid] = s; __syncthreads();
  for (int off = 128; off > 0; off >>= 1) { if (tid < off) sm[tid] += sm[tid + off]; __syncthreads(); }
  if (tid == 0) scales[1] = (float)fmax(sm[0] / co, 1e-5);
}

// ---------------- ternary weight quant: q = clip(rint(w/s), -1, 1) ----------------
__global__ __launch_bounds__(256) void k_wquant(const float* __restrict__ w, long long n4,
                                                const float* __restrict__ sptr,
                                                uint8_t* __restrict__ q) {
  long long i = (long long)blockIdx.x * 256 + threadIdx.x;
  if (i >= n4) return;
  float s = *sptr;
  float4 v = ((const float4*)w)[i];
  int q0 = (int)rintf(v.x / s); q0 = q0 < -1 ? -1 : (q0 > 1 ? 1 : q0);
  int q1 = (int)rintf(v.y / s); q1 = q1 < -1 ? -1 : (q1 > 1 ? 1 : q1);
  int q2 = (int)rintf(v.z / s); q2 = q2 < -1 ? -1 : (q2 > 1 ? 1 : q2);
  int q3 = (int)rintf(v.w / s); q3 = q3 < -1 ? -1 : (q3 > 1 ? 1 : q3);
  uint32_t packed = (uint32_t)(q0 & 0xff) | ((uint32_t)(q1 & 0xff) << 8) |
                    ((uint32_t)(q2 & 0xff) << 16) | ((uint32_t)(q3 & 0xff) << 24);
  ((uint32_t*)q)[i] = packed;
}

__device__ __forceinline__ int q127(float a) {
  float r = rintf(a);
  r = fminf(fmaxf(r, -127.0f), 127.0f);
  return (int)r;
}

// ---------------- fused RMSNorm + per-token int8 quant ----------------
__global__ __launch_bounds__(256) void k_rmsnorm_quant(const float* __restrict__ x,
                                                       const float* __restrict__ g,
                                                       uint8_t* __restrict__ a1,
                                                       float* __restrict__ d1) {
  int t = blockIdx.x;
  int tid = threadIdx.x;
  const float4* xr = (const float4*)(x + (long long)t * DMODEL);
  const float4* gr = (const float4*)g;
  float4 xv[2], gv[2];
  xv[0] = xr[tid]; xv[1] = xr[tid + 256];
  gv[0] = gr[tid]; gv[1] = gr[tid + 256];
  double ss = 0.0;
  for (int p = 0; p < 2; p++) {
    float4 v = xv[p];
    ss += (double)v.x * v.x + (double)v.y * v.y + (double)v.z * v.z + (double)v.w * v.w;
  }
  int lane = tid & 63, wave = tid >> 6;
  for (int off = 32; off > 0; off >>= 1) ss += __shfl_down(ss, off);
  __shared__ double wsum[4];
  if (lane == 0) wsum[wave] = ss;
  __syncthreads();
  double var = (wsum[0] + wsum[1] + wsum[2] + wsum[3]) / (double)DMODEL;
  float r = (float)(1.0 / sqrt(var + 1e-5));
  float h[8];
  h[0] = xv[0].x * r * gv[0].x; h[1] = xv[0].y * r * gv[0].y;
  h[2] = xv[0].z * r * gv[0].z; h[3] = xv[0].w * r * gv[0].w;
  h[4] = xv[1].x * r * gv[1].x; h[5] = xv[1].y * r * gv[1].y;
  h[6] = xv[1].z * r * gv[1].z; h[7] = xv[1].w * r * gv[1].w;
  float am = 0.f;
  for (int k = 0; k < 8; k++) am = fmaxf(am, fabsf(h[k]));
  for (int off = 32; off > 0; off >>= 1) am = fmaxf(am, __shfl_down(am, off));
  __shared__ float wmax[4];
  if (lane == 0) wmax[wave] = am;
  __syncthreads();
  float amc = fmaxf(fmaxf(fmaxf(wmax[0], wmax[1]), fmaxf(wmax[2], wmax[3])), 1e-5f);
  float scale = 127.0f / amc;
  uint32_t* arow = (uint32_t*)(a1 + (long long)t * DMODEL);
  for (int p = 0; p < 2; p++) {
    int q0 = q127(h[p * 4 + 0] * scale);
    int q1 = q127(h[p * 4 + 1] * scale);
    int q2 = q127(h[p * 4 + 2] * scale);
    int q3 = q127(h[p * 4 + 3] * scale);
    arow[tid + p * 256] = (uint32_t)(q0 & 0xff) | ((uint32_t)(q1 & 0xff) << 8) |
                          ((uint32_t)(q2 & 0xff) << 16) | ((uint32_t)(q3 & 0xff) << 24);
  }
  if (tid == 0) d1[t] = amc / 127.0f;
}

// ================= 8-phase 256-tile int8 GEMM core =================
// BM=256, BN=256(rows of B tile), BK=64 bytes. 8 waves (2M x 4N), wave tile 128x64.
// 3-deep LDS buffer (96KB), global_load_lds staging with pre-swizzled source,
// XOR-swizzled ds_read (2-way bank aliasing = free), counted vmcnt(4), setprio MFMA.
template<int NT>
__device__ __forceinline__ void gemm_kloop(
    const uint8_t* gA0, const uint8_t* gA1,
    const uint8_t* gB0, const uint8_t* gB1,
    uint8_t* sA, uint8_t* sB,
    int lA0, int lA1,
    int wm, int wn, int rsel, int koff, v4i (&acc)[8][4])
{
  // prologue: stage tiles 0 (buf0) and 1 (buf1)
  gload16(gA0,      sA + lA0);          gload16(gA1,      sA + lA1);
  gload16(gB0,      sB + lA0);          gload16(gB1,      sB + lA1);
  gload16(gA0 + 64, sA + 16384 + lA0);  gload16(gA1 + 64, sA + 16384 + lA1);
  gload16(gB0 + 64, sB + 16384 + lA0);  gload16(gB1 + 64, sB + 16384 + lA1);
  asm volatile("s_waitcnt vmcnt(4)" ::: "memory");   // tile 0 resident, tile 1 in flight
  __builtin_amdgcn_sched_barrier(0);
  __builtin_amdgcn_s_barrier();

  int cb = 0, nb = 2;
  for (int t = 0; t < NT; ++t) {
    const uint8_t* bA = sA + cb * 16384;
    const uint8_t* bB = sB + cb * 16384;
    int nxo = nb * 16384;
    bool pre = (t + 2) < NT;
    long long ko = (long long)(t + 2) * 64;
    v4i af[4], bf[4];

    // ---- phase 0: A rows 0..63 of wave tile + all B frags; prefetch A of t+2 ----
#pragma unroll
    for (int e = 0; e < 4; ++e)
      af[e] = *(const v4i*)(bA + (wm + e * 16 + rsel) * 64 + koff);
#pragma unroll
    for (int j = 0; j < 4; ++j)
      bf[j] = *(const v4i*)(bB + (wn + j * 16 + rsel) * 64 + koff);
    if (pre) { gload16(gA0 + ko, sA + nxo + lA0); gload16(gA1 + ko, sA + nxo + lA1); }
    __builtin_amdgcn_s_barrier();
    asm volatile("s_waitcnt lgkmcnt(0)" ::: "memory");
    __builtin_amdgcn_sched_barrier(0);
    __builtin_amdgcn_s_setprio(1);
#pragma unroll
    for (int e = 0; e < 4; ++e)
#pragma unroll
      for (int j = 0; j < 4; ++j)
        acc[e][j] = __builtin_amdgcn_mfma_i32_16x16x64_i8(af[e], bf[j], acc[e][j], 0, 0, 0);
    __builtin_amdgcn_s_setprio(0);
    __builtin_amdgcn_s_barrier();

    // ---- phase 1: A rows 64..127 of wave tile; prefetch B of t+2 ----
#pragma unroll
    for (int e = 0; e < 4; ++e)
      af[e] = *(const v4i*)(bA + (wm + (e + 4) * 16 + rsel) * 64 + koff);
    if (pre) { gload16(gB0 + ko, sB + nxo + lA0); gload16(gB1 + ko, sB + nxo + lA1); }
    __builtin_amdgcn_s_barrier();
    asm volatile("s_waitcnt lgkmcnt(0)" ::: "memory");
    __builtin_amdgcn_sched_barrier(0);
    __builtin_amdgcn_s_setprio(1);
#pragma unroll
    for (int e = 0; e < 4; ++e)
#pragma unroll
      for (int j = 0; j < 4; ++j)
        acc[e + 4][j] = __builtin_amdgcn_mfma_i32_16x16x64_i8(af[e], bf[j], acc[e + 4][j], 0, 0, 0);
    __builtin_amdgcn_s_setprio(0);

    // ---- tile boundary: wait t+1's loads (counted, never drain in steady state) ----
    if (t < NT - 1) {
      if (pre) asm volatile("s_waitcnt vmcnt(4)" ::: "memory");
      else     asm volatile("s_waitcnt vmcnt(0)" ::: "memory");
      __builtin_amdgcn_sched_barrier(0);
      __builtin_amdgcn_s_barrier();
    }
    cb = (cb == 2) ? 0 : cb + 1;
    nb = (nb == 2) ? 0 : nb + 1;
  }
}

// ---------------- GEMM1: 256 tokens x (128 value + 128 gate cols), fused SwiGLU ----------------
__global__ __launch_bounds__(512, 2) void k_gemm1_8p(
    const uint8_t* __restrict__ A, const uint8_t* __restrict__ Bq,
    const float* __restrict__ d1, const float* __restrict__ scales,
    float* __restrict__ H2) {
  __shared__ __align__(16) uint8_t smem[98304];
  uint8_t* sA = smem;
  uint8_t* sB = smem + 49152;
  int tid = threadIdx.x, lane = tid & 63, w = tid >> 6;
  int rsel = lane & 15;
  int koff = ((lane >> 4) << 4) ^ (((rsel >> 1) & 3) << 4);
  int wm = (w >> 2) * 128, wn = (w & 3) * 64;

  // bijective XCD swizzle + m-fast (consecutive blocks share the 512KB B panel)
  const int gm = TOKENS / 256;          // 32
  const int gn = HID / 128;             // 64
  int cpx = (gm * gn) >> 3;
  int bid = blockIdx.x;
  int b2 = (bid & 7) * cpx + (bid >> 3);
  int bm = b2 % gm, bn = b2 / gm;
  long long m0 = (long long)bm * 256;
  int n0 = bn * 128;

  // staging precompute: chunk id -> (row, pre-swizzled source column)
  int cid0 = w * 128 + lane, cid1 = cid0 + 64;
  int r0 = cid0 >> 2, r1 = cid1 >> 2;
  int c0 = ((cid0 & 3) ^ ((r0 >> 1) & 3)) << 4;
  int c1 = ((cid1 & 3) ^ ((r1 >> 1) & 3)) << 4;
  const uint8_t* gA0 = A + (m0 + r0) * (long long)DMODEL + c0;
  const uint8_t* gA1 = A + (m0 + r1) * (long long)DMODEL + c1;
  long long br0 = (r0 < 128) ? (long long)(n0 + r0) : (long long)(HID + n0 + r0 - 128);
  long long br1 = (r1 < 128) ? (long long)(n0 + r1) : (long long)(HID + n0 + r1 - 128);
  const uint8_t* gB0 = Bq + br0 * DMODEL + c0;
  const uint8_t* gB1 = Bq + br1 * DMODEL + c1;
  int lA0 = w * 2048, lA1 = lA0 + 1024;

  v4i acc[8][4] = {};
  gemm_kloop<DMODEL / 64>(gA0, gA1, gB0, gB1, sA, sB, lA0, lA1, wm, wn, rsel, koff, acc);

  // ---- epilogue: gate waves publish silu(g*ds) via LDS; value waves write H2 ----
  __syncthreads();
  float sgv = scales[0];
  int q4 = (lane >> 4) << 2;
  bool isV = (wn < 128);
  float* sil = (float*)smem;            // [128][132] padded
#pragma unroll
  for (int half = 0; half < 2; ++half) {
    if (((wm != 0) == (half != 0)) && !isV) {
#pragma unroll
      for (int i = 0; i < 8; ++i) {
#pragma unroll
        for (int r = 0; r < 4; ++r) {
          int ri = i * 16 + q4 + r;
          long long token = m0 + wm + ri;
          float ds = d1[token] * sgv;
#pragma unroll
          for (int j = 0; j < 4; ++j) {
            float g = (float)acc[i][j][r] * ds;
            sil[ri * 132 + (wn - 128) + j * 16 + rsel] = g / (1.0f + expf(-g));
          }
        }
      }
    }
    __syncthreads();
    if (((wm != 0) == (half != 0)) && isV) {
#pragma unroll
      for (int i = 0; i < 8; ++i) {
#pragma unroll
        for (int r = 0; r < 4; ++r) {
          int ri = i * 16 + q4 + r;
          long long token = m0 + wm + ri;
          float ds = d1[token] * sgv;
          float* hrow = H2 + token * HID + n0;
#pragma unroll
          for (int j = 0; j < 4; ++j) {
            float v = (float)acc[i][j][r] * ds;
            hrow[wn + j * 16 + rsel] = v * sil[ri * 132 + wn + j * 16 + rsel];
          }
        }
      }
    }
    __syncthreads();
  }
}

// ---------------- per-token int8 quant of h2 (row of 8192) ----------------
__global__ __launch_bounds__(256) void k_hquant(const float* __restrict__ H2,
                                                uint8_t* __restrict__ A2,
                                                float* __restrict__ d2) {
  int t = blockIdx.x;
  int tid = threadIdx.x;
  const float4* hr = (const float4*)(H2 + (long long)t * HID);
  float4 v[8];
  float am = 0.f;
  for (int p = 0; p < 8; p++) {
    v[p] = hr[tid + p * 256];
    am = fmaxf(am, fmaxf(fmaxf(fabsf(v[p].x), fabsf(v[p].y)), fmaxf(fabsf(v[p].z), fabsf(v[p].w))));
  }
  int lane = tid & 63, wave = tid >> 6;
  for (int off = 32; off > 0; off >>= 1) am = fmaxf(am, __shfl_down(am, off));
  __shared__ float wmax[4];
  if (lane == 0) wmax[wave] = am;
  __syncthreads();
  float amc = fmaxf(fmaxf(fmaxf(wmax[0], wmax[1]), fmaxf(wmax[2], wmax[3])), 1e-5f);
  float scale = 127.0f / amc;
  uint32_t* arow = (uint32_t*)(A2 + (long long)t * HID);
  for (int p = 0; p < 8; p++) {
    int q0 = q127(v[p].x * scale);
    int q1 = q127(v[p].y * scale);
    int q2 = q127(v[p].z * scale);
    int q3 = q127(v[p].w * scale);
    arow[tid + p * 256] = (uint32_t)(q0 & 0xff) | ((uint32_t)(q1 & 0xff) << 8) |
                          ((uint32_t)(q2 & 0xff) << 16) | ((uint32_t)(q3 & 0xff) << 24);
  }
  if (tid == 0) d2[t] = amc / 127.0f;
}

// ---------------- GEMM2: 256 tokens x 256 d_model cols + residual ----------------
__global__ __launch_bounds__(512, 2) void k_gemm2_8p(
    const uint8_t* __restrict__ A2, const uint8_t* __restrict__ Bq,
    const float* __restrict__ d2, const float* __restrict__ scales,
    const float* __restrict__ x, float* __restrict__ out) {
  __shared__ __align__(16) uint8_t smem[98304];
  uint8_t* sA = smem;
  uint8_t* sB = smem + 49152;
  int tid = threadIdx.x, lane = tid & 63, w = tid >> 6;
  int rsel = lane & 15;
  int koff = ((lane >> 4) << 4) ^ (((rsel >> 1) & 3) << 4);
  int wm = (w >> 2) * 128, wn = (w & 3) * 64;

  const int gm = TOKENS / 256;          // 32
  const int gn = DMODEL / 256;          // 8
  int cpx = (gm * gn) >> 3;
  int bid = blockIdx.x;
  int b2 = (bid & 7) * cpx + (bid >> 3);
  int bm = b2 % gm, bn = b2 / gm;
  long long m0 = (long long)bm * 256;
  int n0 = bn * 256;

  int cid0 = w * 128 + lane, cid1 = cid0 + 64;
  int r0 = cid0 >> 2, r1 = cid1 >> 2;
  int c0 = ((cid0 & 3) ^ ((r0 >> 1) & 3)) << 4;
  int c1 = ((cid1 & 3) ^ ((r1 >> 1) & 3)) << 4;
  const uint8_t* gA0 = A2 + (m0 + r0) * (long long)HID + c0;
  const uint8_t* gA1 = A2 + (m0 + r1) * (long long)HID + c1;
  const uint8_t* gB0 = Bq + (long long)(n0 + r0) * HID + c0;
  const uint8_t* gB1 = Bq + (long long)(n0 + r1) * HID + c1;
  int lA0 = w * 2048, lA1 = lA0 + 1024;

  v4i acc[8][4] = {};
  gemm_kloop<HID / 64>(gA0, gA1, gB0, gB1, sA, sB, lA0, lA1, wm, wn, rsel, koff, acc);

  float so = scales[1];
  int q4 = (lane >> 4) << 2;
#pragma unroll
  for (int i = 0; i < 8; ++i) {
#pragma unroll
    for (int r = 0; r < 4; ++r) {
      long long token = m0 + wm + i * 16 + q4 + r;
      float ds = d2[token] * so;
      const float* xr = x + token * DMODEL;
      float* orow = out + token * DMODEL;
#pragma unroll
      for (int j = 0; j < 4; ++j) {
        int c = n0 + wn + j * 16 + rsel;
        orow[c] = xr[c] + (float)acc[i][j][r] * ds;
      }
    }
  }
}

extern "C" void kernel_launch(void* const* d_in, const int* in_sizes, int n_in,
                              void* d_out, int out_size, void* d_ws, size_t ws_size,
                              hipStream_t stream) {
  const float* x      = (const float*)d_in[0];
  const float* norm_w = (const float*)d_in[1];
  const float* w_gv   = (const float*)d_in[2];
  const float* w_out  = (const float*)d_in[3];
  float* out = (float*)d_out;

  char* ws = (char*)d_ws;
  size_t off = 0;
  float*   H2    = (float*)(ws + off);   off += (size_t)TOKENS * HID * 4;   // 268 MB
  uint8_t* A2    = (uint8_t*)(ws + off); off += (size_t)TOKENS * HID;       // 67 MB
  uint8_t* Wqgv  = (uint8_t*)(ws + off); off += (size_t)2 * HID * DMODEL;   // 33.5 MB
  uint8_t* Wqout = (uint8_t*)(ws + off); off += (size_t)DMODEL * HID;       // 16.8 MB
  uint8_t* A1    = (uint8_t*)(ws + off); off += (size_t)TOKENS * DMODEL;    // 16.8 MB
  float*   d1    = (float*)(ws + off);   off += (size_t)TOKENS * 4;
  float*   d2    = (float*)(ws + off);   off += (size_t)TOKENS * 4;
  double*  pgv   = (double*)(ws + off);  off += 1024 * 8;
  double*  pout  = (double*)(ws + off);  off += 512 * 8;
  float*   scales = (float*)(ws + off);  off += 16;

  const long long ngv = (long long)2 * HID * DMODEL;   // 33554432
  const long long nout = (long long)DMODEL * HID;      // 16777216

  k_abssum<<<1024, 256, 0, stream>>>(w_gv, ngv / 4, pgv);
  k_abssum<<<512, 256, 0, stream>>>(w_out, nout / 4, pout);
  k_finalize<<<1, 256, 0, stream>>>(pgv, 1024, (double)ngv, pout, 512, (double)nout, scales);
  k_wquant<<<(int)((ngv / 4 + 255) / 256), 256, 0, stream>>>(w_gv, ngv / 4, scales + 0, Wqgv);
  k_wquant<<<(int)((nout / 4 + 255) / 256), 256, 0, stream>>>(w_out, nout / 4, scales + 1, Wqout);
  k_rmsnorm_quant<<<TOKENS, 256, 0, stream>>>(x, norm_w, A1, d1);
  k_gemm1_8p<<<dim3((TOKENS / 256) * (HID / 128)), 512, 0, stream>>>(A1, Wqgv, d1, scales, H2);
  k_hquant<<<TOKENS, 256, 0, stream>>>(H2, A2, d2);
  k_gemm2_8p<<<dim3((TOKENS / 256) * (DMODEL / 256)), 512, 0, stream>>>(A2, Wqout, d2, scales, x, out);
}

// Round 3
// 857.206 us; speedup vs baseline: 1.1948x; 1.1948x over previous
//
#include <hip/hip_runtime.h>
#include <stdint.h>
#include <math.h>

#define TOKENS 8192
#define DMODEL 2048
#define HID    8192

// Block tile: 128 tokens (BM) x 256 B-rows (BR), BK=64 bytes.
// 8 waves (2M x 4N), wave tile 64x64, acc[4][4] = 64 AGPR -> <=128 regs/thread.
// 2-deep LDS (2 x 24KB = 48KB) -> 2 independent blocks/CU (16 waves).
#define TILE_B 24576

typedef __attribute__((ext_vector_type(4))) int v4i;

typedef const __attribute__((address_space(1))) uint32_t gu32;
typedef __attribute__((address_space(3))) uint32_t lu32;

__device__ __forceinline__ void gload16(const void* g, void* l) {
  // async global->LDS DMA; dest = wave-uniform base + lane*16
  __builtin_amdgcn_global_load_lds((gu32*)g, (lu32*)l, 16, 0, 0);
}

// ---------------- weight absmean: partial |w| sums (fp64) ----------------
__global__ __launch_bounds__(256) void k_abssum(const float* __restrict__ w, long long n4,
                                                double* __restrict__ partial) {
  long long i0 = (long long)blockIdx.x * 256 + threadIdx.x;
  long long stride = (long long)gridDim.x * 256;
  const float4* w4 = (const float4*)w;
  double s = 0.0;
  for (long long i = i0; i < n4; i += stride) {
    float4 v = w4[i];
    s += (double)fabsf(v.x) + (double)fabsf(v.y) + (double)fabsf(v.z) + (double)fabsf(v.w);
  }
  __shared__ double sm[256];
  sm[threadIdx.x] = s;
  __syncthreads();
  for (int off = 128; off > 0; off >>= 1) {
    if ((int)threadIdx.x < off) sm[threadIdx.x] += sm[threadIdx.x + off];
    __syncthreads();
  }
  if (threadIdx.x == 0) partial[blockIdx.x] = sm[0];
}

// ---------------- finalize: s = max(mean|w|, 1e-5) for both weights ----------------
__global__ __launch_bounds__(256) void k_finalize(const double* __restrict__ pg, int ng, double cg,
                                                  const double* __restrict__ po, int no, double co,
                                                  float* __restrict__ scales) {
  __shared__ double sm[256];
  int tid = threadIdx.x;
  double s = 0.0;
  for (int i = tid; i < ng; i += 256) s += pg[i];
  sm[tid] = s; __syncthreads();
  for (int off = 128; off > 0; off >>= 1) { if (tid < off) sm[tid] += sm[tid + off]; __syncthreads(); }
  if (tid == 0) scales[0] = (float)fmax(sm[0] / cg, 1e-5);
  __syncthreads();
  s = 0.0;
  for (int i = tid; i < no; i += 256) s += po[i];
  sm[tid] = s; __syncthreads();
  for (int off = 128; off > 0; off >>= 1) { if (tid < off) sm[tid] += sm[tid + off]; __syncthreads(); }
  if (tid == 0) scales[1] = (float)fmax(sm[0] / co, 1e-5);
}

// ---------------- ternary weight quant: q = clip(rint(w/s), -1, 1) ----------------
__global__ __launch_bounds__(256) void k_wquant(const float* __restrict__ w, long long n4,
                                                const float* __restrict__ sptr,
                                                uint8_t* __restrict__ q) {
  long long i = (long long)blockIdx.x * 256 + threadIdx.x;
  if (i >= n4) return;
  float s = *sptr;
  float4 v = ((const float4*)w)[i];
  int q0 = (int)rintf(v.x / s); q0 = q0 < -1 ? -1 : (q0 > 1 ? 1 : q0);
  int q1 = (int)rintf(v.y / s); q1 = q1 < -1 ? -1 : (q1 > 1 ? 1 : q1);
  int q2 = (int)rintf(v.z / s); q2 = q2 < -1 ? -1 : (q2 > 1 ? 1 : q2);
  int q3 = (int)rintf(v.w / s); q3 = q3 < -1 ? -1 : (q3 > 1 ? 1 : q3);
  uint32_t packed = (uint32_t)(q0 & 0xff) | ((uint32_t)(q1 & 0xff) << 8) |
                    ((uint32_t)(q2 & 0xff) << 16) | ((uint32_t)(q3 & 0xff) << 24);
  ((uint32_t*)q)[i] = packed;
}

__device__ __forceinline__ int q127(float a) {
  float r = rintf(a);
  r = fminf(fmaxf(r, -127.0f), 127.0f);
  return (int)r;
}

// ---------------- fused RMSNorm + per-token int8 quant ----------------
__global__ __launch_bounds__(256) void k_rmsnorm_quant(const float* __restrict__ x,
                                                       const float* __restrict__ g,
                                                       uint8_t* __restrict__ a1,
                                                       float* __restrict__ d1) {
  int t = blockIdx.x;
  int tid = threadIdx.x;
  const float4* xr = (const float4*)(x + (long long)t * DMODEL);
  const float4* gr = (const float4*)g;
  float4 xv[2], gv[2];
  xv[0] = xr[tid]; xv[1] = xr[tid + 256];
  gv[0] = gr[tid]; gv[1] = gr[tid + 256];
  double ss = 0.0;
  for (int p = 0; p < 2; p++) {
    float4 v = xv[p];
    ss += (double)v.x * v.x + (double)v.y * v.y + (double)v.z * v.z + (double)v.w * v.w;
  }
  int lane = tid & 63, wave = tid >> 6;
  for (int off = 32; off > 0; off >>= 1) ss += __shfl_down(ss, off);
  __shared__ double wsum[4];
  if (lane == 0) wsum[wave] = ss;
  __syncthreads();
  double var = (wsum[0] + wsum[1] + wsum[2] + wsum[3]) / (double)DMODEL;
  float r = (float)(1.0 / sqrt(var + 1e-5));
  float h[8];
  h[0] = xv[0].x * r * gv[0].x; h[1] = xv[0].y * r * gv[0].y;
  h[2] = xv[0].z * r * gv[0].z; h[3] = xv[0].w * r * gv[0].w;
  h[4] = xv[1].x * r * gv[1].x; h[5] = xv[1].y * r * gv[1].y;
  h[6] = xv[1].z * r * gv[1].z; h[7] = xv[1].w * r * gv[1].w;
  float am = 0.f;
  for (int k = 0; k < 8; k++) am = fmaxf(am, fabsf(h[k]));
  for (int off = 32; off > 0; off >>= 1) am = fmaxf(am, __shfl_down(am, off));
  __shared__ float wmax[4];
  if (lane == 0) wmax[wave] = am;
  __syncthreads();
  float amc = fmaxf(fmaxf(fmaxf(wmax[0], wmax[1]), fmaxf(wmax[2], wmax[3])), 1e-5f);
  float scale = 127.0f / amc;
  uint32_t* arow = (uint32_t*)(a1 + (long long)t * DMODEL);
  for (int p = 0; p < 2; p++) {
    int q0 = q127(h[p * 4 + 0] * scale);
    int q1 = q127(h[p * 4 + 1] * scale);
    int q2 = q127(h[p * 4 + 2] * scale);
    int q3 = q127(h[p * 4 + 3] * scale);
    arow[tid + p * 256] = (uint32_t)(q0 & 0xff) | ((uint32_t)(q1 & 0xff) << 8) |
                          ((uint32_t)(q2 & 0xff) << 16) | ((uint32_t)(q3 & 0xff) << 24);
  }
  if (tid == 0) d1[t] = amc / 127.0f;
}

// ================= shared K-loop: stage -> compute -> sync (m97 structure) =================
// Per thread: 1 A-gload + 2 B-gloads per tile; 4+4 ds_read_b128; 16 MFMA.
// Conflict-free XOR swizzle (2-way aliasing) on both stage-source and read (involution).
template<int NT>
__device__ __forceinline__ void kloop(const uint8_t* srcA, const uint8_t* srcB0,
                                      const uint8_t* srcB1, uint8_t* smem,
                                      int w, int rsel, int koff, int wm, int wn,
                                      v4i (&acc)[4][4]) {
  int ldsA = w * 1024;
  int ldsB = 8192 + w * 2048;
  // prologue: stage tile 0
  gload16(srcA,  smem + ldsA);
  gload16(srcB0, smem + ldsB);
  gload16(srcB1, smem + ldsB + 1024);
  __syncthreads();
  for (int t = 0; t < NT; ++t) {
    if (t + 1 < NT) {
      int nb = ((t + 1) & 1) * TILE_B;
      int ko = (t + 1) * 64;
      gload16(srcA + ko,  smem + nb + ldsA);
      gload16(srcB0 + ko, smem + nb + ldsB);
      gload16(srcB1 + ko, smem + nb + ldsB + 1024);
    }
    const uint8_t* bA = smem + (t & 1) * TILE_B;
    const uint8_t* bB = bA + 8192;
    v4i af[4], bf[4];
#pragma unroll
    for (int e = 0; e < 4; ++e)
      af[e] = *(const v4i*)(bA + (wm + e * 16 + rsel) * 64 + koff);
#pragma unroll
    for (int j = 0; j < 4; ++j)
      bf[j] = *(const v4i*)(bB + (wn + j * 16 + rsel) * 64 + koff);
    __builtin_amdgcn_s_setprio(1);
#pragma unroll
    for (int e = 0; e < 4; ++e)
#pragma unroll
      for (int j = 0; j < 4; ++j)
        acc[e][j] = __builtin_amdgcn_mfma_i32_16x16x64_i8(af[e], bf[j], acc[e][j], 0, 0, 0);
    __builtin_amdgcn_s_setprio(0);
    __syncthreads();   // drains vm+lgkm; sibling block covers the stall
  }
}

// ---------------- GEMM1: 128 tokens x 128 out-cols (64v+64g per N-wave pair), fused SwiGLU ----------------
__global__ __launch_bounds__(512, 4) void k_gemm1_v3(
    const uint8_t* __restrict__ A, const uint8_t* __restrict__ Bq,
    const float* __restrict__ d1, const float* __restrict__ scales,
    float* __restrict__ H2) {
  __shared__ __align__(16) uint8_t smem[128 * 132 * 4];   // >= 2*TILE_B; epilogue exchange
  int tid = threadIdx.x, lane = tid & 63, w = tid >> 6;
  int rsel = lane & 15;
  int koff = ((lane >> 4) << 4) ^ (((rsel >> 1) & 3) << 4);
  int wm = (w >> 2) * 64, wn = (w & 3) * 64;

  // XCD-contiguous, n-fast within groups of 4 bm (A window ~1MB L2-resident)
  const int gm = TOKENS / 128;    // 64
  const int gn = HID / 128;       // 64
  int bid = blockIdx.x;
  int xcd = bid & 7;
  int loc = bid >> 3;             // [0, 512)
  int g = loc >> 8;               // {0,1}
  int i5 = loc & 255;
  int bn = i5 >> 2;               // [0,64)
  int bm = xcd * 8 + g * 4 + (i5 & 3);
  long long m0 = (long long)bm * 128;
  int n0 = bn * 128;
  (void)gm; (void)gn;

  // staging source (pre-swizzled column = involution of read swizzle)
  int cidA = w * 64 + lane;                 // [0,512)
  int rA = cidA >> 2;
  int cA = ((cidA & 3) ^ ((rA >> 1) & 3)) << 4;
  int cidB0 = w * 128 + lane, cidB1 = cidB0 + 64;   // [0,1024)
  int rB0 = cidB0 >> 2, rB1 = cidB1 >> 2;
  int cB0 = ((cidB0 & 3) ^ ((rB0 >> 1) & 3)) << 4;
  int cB1 = ((cidB1 & 3) ^ ((rB1 >> 1) & 3)) << 4;
  const uint8_t* srcA = A + (m0 + rA) * (long long)DMODEL + cA;
  long long gr0 = (rB0 < 128) ? (long long)(n0 + rB0) : (long long)(HID + n0 + rB0 - 128);
  long long gr1 = (rB1 < 128) ? (long long)(n0 + rB1) : (long long)(HID + n0 + rB1 - 128);
  const uint8_t* srcB0 = Bq + gr0 * DMODEL + cB0;
  const uint8_t* srcB1 = Bq + gr1 * DMODEL + cB1;

  v4i acc[4][4] = {};
  kloop<DMODEL / 64>(srcA, srcB0, srcB1, smem, w, rsel, koff, wm, wn, acc);

  // ---- epilogue: gate waves (wn>=128) publish silu via LDS; value waves write H2 ----
  float sgv = scales[0];
  int q4 = (lane >> 4) << 2;
  float* sil = (float*)smem;      // [128 tokens][132]
  if (wn >= 128) {
#pragma unroll
    for (int i = 0; i < 4; ++i) {
#pragma unroll
      for (int r = 0; r < 4; ++r) {
        int ri = wm + i * 16 + q4 + r;
        float ds = d1[m0 + ri] * sgv;
#pragma unroll
        for (int j = 0; j < 4; ++j) {
          float gg = (float)acc[i][j][r] * ds;
          sil[ri * 132 + (wn - 128) + j * 16 + rsel] = gg / (1.0f + expf(-gg));
        }
      }
    }
  }
  __syncthreads();
  if (wn < 128) {
#pragma unroll
    for (int i = 0; i < 4; ++i) {
#pragma unroll
      for (int r = 0; r < 4; ++r) {
        int ri = wm + i * 16 + q4 + r;
        long long token = m0 + ri;
        float ds = d1[token] * sgv;
        float* hrow = H2 + token * HID + n0;
#pragma unroll
        for (int j = 0; j < 4; ++j) {
          float v = (float)acc[i][j][r] * ds;
          hrow[wn + j * 16 + rsel] = v * sil[ri * 132 + wn + j * 16 + rsel];
        }
      }
    }
  }
}

// ---------------- per-token int8 quant of h2 (row of 8192) ----------------
__global__ __launch_bounds__(256) void k_hquant(const float* __restrict__ H2,
                                                uint8_t* __restrict__ A2,
                                                float* __restrict__ d2) {
  int t = blockIdx.x;
  int tid = threadIdx.x;
  const float4* hr = (const float4*)(H2 + (long long)t * HID);
  float4 v[8];
  float am = 0.f;
  for (int p = 0; p < 8; p++) {
    v[p] = hr[tid + p * 256];
    am = fmaxf(am, fmaxf(fmaxf(fabsf(v[p].x), fabsf(v[p].y)), fmaxf(fabsf(v[p].z), fabsf(v[p].w))));
  }
  int lane = tid & 63, wave = tid >> 6;
  for (int off = 32; off > 0; off >>= 1) am = fmaxf(am, __shfl_down(am, off));
  __shared__ float wmax[4];
  if (lane == 0) wmax[wave] = am;
  __syncthreads();
  float amc = fmaxf(fmaxf(fmaxf(wmax[0], wmax[1]), fmaxf(wmax[2], wmax[3])), 1e-5f);
  float scale = 127.0f / amc;
  uint32_t* arow = (uint32_t*)(A2 + (long long)t * HID);
  for (int p = 0; p < 8; p++) {
    int q0 = q127(v[p].x * scale);
    int q1 = q127(v[p].y * scale);
    int q2 = q127(v[p].z * scale);
    int q3 = q127(v[p].w * scale);
    arow[tid + p * 256] = (uint32_t)(q0 & 0xff) | ((uint32_t)(q1 & 0xff) << 8) |
                          ((uint32_t)(q2 & 0xff) << 16) | ((uint32_t)(q3 & 0xff) << 24);
  }
  if (tid == 0) d2[t] = amc / 127.0f;
}

// ---------------- GEMM2: 128 tokens x 256 d_model cols + residual ----------------
__global__ __launch_bounds__(512, 4) void k_gemm2_v3(
    const uint8_t* __restrict__ A2, const uint8_t* __restrict__ Bq,
    const float* __restrict__ d2, const float* __restrict__ scales,
    const float* __restrict__ x, float* __restrict__ out) {
  __shared__ __align__(16) uint8_t smem[2 * TILE_B];
  int tid = threadIdx.x, lane = tid & 63, w = tid >> 6;
  int rsel = lane & 15;
  int koff = ((lane >> 4) << 4) ^ (((rsel >> 1) & 3) << 4);
  int wm = (w >> 2) * 64, wn = (w & 3) * 64;

  // grid 64 x 8 = 512; per XCD 8bm x 8bn, groups of 2 bm (A window 2MB)
  int bid = blockIdx.x;
  int xcd = bid & 7;
  int loc = bid >> 3;             // [0,64)
  int g = loc >> 4;               // [0,4)
  int i5 = loc & 15;
  int bn = i5 >> 1;               // [0,8)
  int bm = xcd * 8 + g * 2 + (i5 & 1);
  long long m0 = (long long)bm * 128;
  int n0 = bn * 256;

  int cidA = w * 64 + lane;
  int rA = cidA >> 2;
  int cA = ((cidA & 3) ^ ((rA >> 1) & 3)) << 4;
  int cidB0 = w * 128 + lane, cidB1 = cidB0 + 64;
  int rB0 = cidB0 >> 2, rB1 = cidB1 >> 2;
  int cB0 = ((cidB0 & 3) ^ ((rB0 >> 1) & 3)) << 4;
  int cB1 = ((cidB1 & 3) ^ ((rB1 >> 1) & 3)) << 4;
  const uint8_t* srcA = A2 + (m0 + rA) * (long long)HID + cA;
  const uint8_t* srcB0 = Bq + (long long)(n0 + rB0) * HID + cB0;
  const uint8_t* srcB1 = Bq + (long long)(n0 + rB1) * HID + cB1;

  v4i acc[4][4] = {};
  kloop<HID / 64>(srcA, srcB0, srcB1, smem, w, rsel, koff, wm, wn, acc);

  float so = scales[1];
  int q4 = (lane >> 4) << 2;
#pragma unroll
  for (int i = 0; i < 4; ++i) {
#pragma unroll
    for (int r = 0; r < 4; ++r) {
      long long token = m0 + wm + i * 16 + q4 + r;
      float ds = d2[token] * so;
      const float* xr = x + token * DMODEL;
      float* orow = out + token * DMODEL;
#pragma unroll
      for (int j = 0; j < 4; ++j) {
        int c = n0 + wn + j * 16 + rsel;
        orow[c] = xr[c] + (float)acc[i][j][r] * ds;
      }
    }
  }
}

extern "C" void kernel_launch(void* const* d_in, const int* in_sizes, int n_in,
                              void* d_out, int out_size, void* d_ws, size_t ws_size,
                              hipStream_t stream) {
  const float* x      = (const float*)d_in[0];
  const float* norm_w = (const float*)d_in[1];
  const float* w_gv   = (const float*)d_in[2];
  const float* w_out  = (const float*)d_in[3];
  float* out = (float*)d_out;

  char* ws = (char*)d_ws;
  size_t off = 0;
  float*   H2    = (float*)(ws + off);   off += (size_t)TOKENS * HID * 4;   // 268 MB
  uint8_t* A2    = (uint8_t*)(ws + off); off += (size_t)TOKENS * HID;       // 67 MB
  uint8_t* Wqgv  = (uint8_t*)(ws + off); off += (size_t)2 * HID * DMODEL;   // 33.5 MB
  uint8_t* Wqout = (uint8_t*)(ws + off); off += (size_t)DMODEL * HID;       // 16.8 MB
  uint8_t* A1    = (uint8_t*)(ws + off); off += (size_t)TOKENS * DMODEL;    // 16.8 MB
  float*   d1    = (float*)(ws + off);   off += (size_t)TOKENS * 4;
  float*   d2    = (float*)(ws + off);   off += (size_t)TOKENS * 4;
  double*  pgv   = (double*)(ws + off);  off += 1024 * 8;
  double*  pout  = (double*)(ws + off);  off += 512 * 8;
  float*   scales = (float*)(ws + off);  off += 16;

  const long long ngv = (long long)2 * HID * DMODEL;   // 33554432
  const long long nout = (long long)DMODEL * HID;      // 16777216

  k_abssum<<<1024, 256, 0, stream>>>(w_gv, ngv / 4, pgv);
  k_abssum<<<512, 256, 0, stream>>>(w_out, nout / 4, pout);
  k_finalize<<<1, 256, 0, stream>>>(pgv, 1024, (double)ngv, pout, 512, (double)nout, scales);
  k_wquant<<<(int)((ngv / 4 + 255) / 256), 256, 0, stream>>>(w_gv, ngv / 4, scales + 0, Wqgv);
  k_wquant<<<(int)((nout / 4 + 255) / 256), 256, 0, stream>>>(w_out, nout / 4, scales + 1, Wqout);
  k_rmsnorm_quant<<<TOKENS, 256, 0, stream>>>(x, norm_w, A1, d1);
  k_gemm1_v3<<<dim3((TOKENS / 128) * (HID / 128)), 512, 0, stream>>>(A1, Wqgv, d1, scales, H2);
  k_hquant<<<TOKENS, 256, 0, stream>>>(H2, A2, d2);
  k_gemm2_v3<<<dim3((TOKENS / 128) * (DMODEL / 256)), 512, 0, stream>>>(A2, Wqout, d2, scales, x, out);
}

// Round 4
// 838.008 us; speedup vs baseline: 1.2222x; 1.0229x over previous
//
#include <hip/hip_runtime.h>
#include <stdint.h>
#include <math.h>

#define TOKENS 8192
#define DMODEL 2048
#define HID    8192

// Block tile: 128 tokens (BM) x 256 B-rows (BR), BK=64 bytes.
// 8 waves (2M x 4N), wave tile 64x64, acc[4][4] = 64 AGPR -> <=128 regs/thread.
// 3-deep LDS pipeline (3 x 24KB = 72KB) -> 2 blocks/CU (16 waves), counted vmcnt.
#define TILE_B 24576

typedef __attribute__((ext_vector_type(4))) int v4i;

typedef const __attribute__((address_space(1))) uint32_t gu32;
typedef __attribute__((address_space(3))) uint32_t lu32;

__device__ __forceinline__ void gload16(const void* g, void* l) {
  // async global->LDS DMA; dest = wave-uniform base + lane*16
  __builtin_amdgcn_global_load_lds((gu32*)g, (lu32*)l, 16, 0, 0);
}

// ---------------- weight absmean: partial |w| sums (fp64) ----------------
__global__ __launch_bounds__(256) void k_abssum(const float* __restrict__ w, long long n4,
                                                double* __restrict__ partial) {
  long long i0 = (long long)blockIdx.x * 256 + threadIdx.x;
  long long stride = (long long)gridDim.x * 256;
  const float4* w4 = (const float4*)w;
  double s = 0.0;
  for (long long i = i0; i < n4; i += stride) {
    float4 v = w4[i];
    s += (double)fabsf(v.x) + (double)fabsf(v.y) + (double)fabsf(v.z) + (double)fabsf(v.w);
  }
  __shared__ double sm[256];
  sm[threadIdx.x] = s;
  __syncthreads();
  for (int off = 128; off > 0; off >>= 1) {
    if ((int)threadIdx.x < off) sm[threadIdx.x] += sm[threadIdx.x + off];
    __syncthreads();
  }
  if (threadIdx.x == 0) partial[blockIdx.x] = sm[0];
}

// ---------------- finalize: s = max(mean|w|, 1e-5) for both weights ----------------
__global__ __launch_bounds__(256) void k_finalize(const double* __restrict__ pg, int ng, double cg,
                                                  const double* __restrict__ po, int no, double co,
                                                  float* __restrict__ scales) {
  __shared__ double sm[256];
  int tid = threadIdx.x;
  double s = 0.0;
  for (int i = tid; i < ng; i += 256) s += pg[i];
  sm[tid] = s; __syncthreads();
  for (int off = 128; off > 0; off >>= 1) { if (tid < off) sm[tid] += sm[tid + off]; __syncthreads(); }
  if (tid == 0) scales[0] = (float)fmax(sm[0] / cg, 1e-5);
  __syncthreads();
  s = 0.0;
  for (int i = tid; i < no; i += 256) s += po[i];
  sm[tid] = s; __syncthreads();
  for (int off = 128; off > 0; off >>= 1) { if (tid < off) sm[tid] += sm[tid + off]; __syncthreads(); }
  if (tid == 0) scales[1] = (float)fmax(sm[0] / co, 1e-5);
}

// ---------------- ternary weight quant: q = clip(rint(w/s), -1, 1) ----------------
__global__ __launch_bounds__(256) void k_wquant(const float* __restrict__ w, long long n4,
                                                const float* __restrict__ sptr,
                                                uint8_t* __restrict__ q) {
  long long i = (long long)blockIdx.x * 256 + threadIdx.x;
  if (i >= n4) return;
  float s = *sptr;
  float4 v = ((const float4*)w)[i];
  int q0 = (int)rintf(v.x / s); q0 = q0 < -1 ? -1 : (q0 > 1 ? 1 : q0);
  int q1 = (int)rintf(v.y / s); q1 = q1 < -1 ? -1 : (q1 > 1 ? 1 : q1);
  int q2 = (int)rintf(v.z / s); q2 = q2 < -1 ? -1 : (q2 > 1 ? 1 : q2);
  int q3 = (int)rintf(v.w / s); q3 = q3 < -1 ? -1 : (q3 > 1 ? 1 : q3);
  uint32_t packed = (uint32_t)(q0 & 0xff) | ((uint32_t)(q1 & 0xff) << 8) |
                    ((uint32_t)(q2 & 0xff) << 16) | ((uint32_t)(q3 & 0xff) << 24);
  ((uint32_t*)q)[i] = packed;
}

__device__ __forceinline__ int q127(float a) {
  float r = rintf(a);
  r = fminf(fmaxf(r, -127.0f), 127.0f);
  return (int)r;
}

// ---------------- fused RMSNorm + per-token int8 quant ----------------
__global__ __launch_bounds__(256) void k_rmsnorm_quant(const float* __restrict__ x,
                                                       const float* __restrict__ g,
                                                       uint8_t* __restrict__ a1,
                                                       float* __restrict__ d1) {
  int t = blockIdx.x;
  int tid = threadIdx.x;
  const float4* xr = (const float4*)(x + (long long)t * DMODEL);
  const float4* gr = (const float4*)g;
  float4 xv[2], gv[2];
  xv[0] = xr[tid]; xv[1] = xr[tid + 256];
  gv[0] = gr[tid]; gv[1] = gr[tid + 256];
  double ss = 0.0;
  for (int p = 0; p < 2; p++) {
    float4 v = xv[p];
    ss += (double)v.x * v.x + (double)v.y * v.y + (double)v.z * v.z + (double)v.w * v.w;
  }
  int lane = tid & 63, wave = tid >> 6;
  for (int off = 32; off > 0; off >>= 1) ss += __shfl_down(ss, off);
  __shared__ double wsum[4];
  if (lane == 0) wsum[wave] = ss;
  __syncthreads();
  double var = (wsum[0] + wsum[1] + wsum[2] + wsum[3]) / (double)DMODEL;
  float r = (float)(1.0 / sqrt(var + 1e-5));
  float h[8];
  h[0] = xv[0].x * r * gv[0].x; h[1] = xv[0].y * r * gv[0].y;
  h[2] = xv[0].z * r * gv[0].z; h[3] = xv[0].w * r * gv[0].w;
  h[4] = xv[1].x * r * gv[1].x; h[5] = xv[1].y * r * gv[1].y;
  h[6] = xv[1].z * r * gv[1].z; h[7] = xv[1].w * r * gv[1].w;
  float am = 0.f;
  for (int k = 0; k < 8; k++) am = fmaxf(am, fabsf(h[k]));
  for (int off = 32; off > 0; off >>= 1) am = fmaxf(am, __shfl_down(am, off));
  __shared__ float wmax[4];
  if (lane == 0) wmax[wave] = am;
  __syncthreads();
  float amc = fmaxf(fmaxf(fmaxf(wmax[0], wmax[1]), fmaxf(wmax[2], wmax[3])), 1e-5f);
  float scale = 127.0f / amc;
  uint32_t* arow = (uint32_t*)(a1 + (long long)t * DMODEL);
  for (int p = 0; p < 2; p++) {
    int q0 = q127(h[p * 4 + 0] * scale);
    int q1 = q127(h[p * 4 + 1] * scale);
    int q2 = q127(h[p * 4 + 2] * scale);
    int q3 = q127(h[p * 4 + 3] * scale);
    arow[tid + p * 256] = (uint32_t)(q0 & 0xff) | ((uint32_t)(q1 & 0xff) << 8) |
                          ((uint32_t)(q2 & 0xff) << 16) | ((uint32_t)(q3 & 0xff) << 24);
  }
  if (tid == 0) d1[t] = amc / 127.0f;
}

// ================= shared K-loop: 3-deep pipeline, counted vmcnt =================
// Per tile: issue stage(t+2); ds_read frags(t); lgkmcnt(0); 16 MFMA; vmcnt(3); barrier.
// vmcnt(3) leaves t+2's loads in flight (never drain to 0 in steady state);
// stage issued 2 tiles (~1300 cyc) ahead of use -> covers HBM latency.
// Safety: overwrite of buf[(t+2)%3] = buf[(t-1)%3] is safe because all waves'
// ds_reads of t-1 completed (lgkmcnt(0)) before the barrier ending tile t-1.
template<int NT>
__device__ __forceinline__ void kloop(const uint8_t* srcA, const uint8_t* srcB0,
                                      const uint8_t* srcB1, uint8_t* smem,
                                      int w, int rsel, int koff, int wm, int wn,
                                      v4i (&acc)[4][4]) {
  int ldsA = w * 1024;
  int ldsB = 8192 + w * 2048;
  // prologue: stage tiles 0 and 1
  gload16(srcA,       smem + ldsA);
  gload16(srcB0,      smem + ldsB);
  gload16(srcB1,      smem + ldsB + 1024);
  gload16(srcA + 64,  smem + TILE_B + ldsA);
  gload16(srcB0 + 64, smem + TILE_B + ldsB);
  gload16(srcB1 + 64, smem + TILE_B + ldsB + 1024);
  asm volatile("s_waitcnt vmcnt(3)" ::: "memory");   // tile 0 resident, tile 1 in flight
  __builtin_amdgcn_sched_barrier(0);
  __builtin_amdgcn_s_barrier();

  int cur = 0, nxt = 2 * TILE_B;
#pragma unroll 3
  for (int t = 0; t < NT; ++t) {
    if (t + 2 < NT) {
      int ko = (t + 2) * 64;
      gload16(srcA + ko,  smem + nxt + ldsA);
      gload16(srcB0 + ko, smem + nxt + ldsB);
      gload16(srcB1 + ko, smem + nxt + ldsB + 1024);
    }
    const uint8_t* bA = smem + cur;
    const uint8_t* bB = bA + 8192;
    v4i af[4], bf[4];
#pragma unroll
    for (int e = 0; e < 4; ++e)
      af[e] = *(const v4i*)(bA + (wm + e * 16 + rsel) * 64 + koff);
#pragma unroll
    for (int j = 0; j < 4; ++j)
      bf[j] = *(const v4i*)(bB + (wn + j * 16 + rsel) * 64 + koff);
    asm volatile("s_waitcnt lgkmcnt(0)" ::: "memory");
    __builtin_amdgcn_sched_barrier(0);
    __builtin_amdgcn_s_setprio(1);
#pragma unroll
    for (int e = 0; e < 4; ++e)
#pragma unroll
      for (int j = 0; j < 4; ++j)
        acc[e][j] = __builtin_amdgcn_mfma_i32_16x16x64_i8(af[e], bf[j], acc[e][j], 0, 0, 0);
    __builtin_amdgcn_s_setprio(0);
    if (t < NT - 1) {
      if (t + 2 < NT) asm volatile("s_waitcnt vmcnt(3)" ::: "memory");  // t+1 resident
      else            asm volatile("s_waitcnt vmcnt(0)" ::: "memory");  // drain tail
      __builtin_amdgcn_sched_barrier(0);
      __builtin_amdgcn_s_barrier();
    }
    cur += TILE_B; if (cur == 3 * TILE_B) cur = 0;
    nxt += TILE_B; if (nxt == 3 * TILE_B) nxt = 0;
  }
}

// ---------------- GEMM1: 128 tokens x 128 out-cols (64v+64g per N-wave pair), fused SwiGLU ----------------
__global__ __launch_bounds__(512, 4) void k_gemm1_v4(
    const uint8_t* __restrict__ A, const uint8_t* __restrict__ Bq,
    const float* __restrict__ d1, const float* __restrict__ scales,
    float* __restrict__ H2) {
  __shared__ __align__(16) uint8_t smem[3 * TILE_B];   // 72KB >= epilogue 128*132*4
  int tid = threadIdx.x, lane = tid & 63, w = tid >> 6;
  int rsel = lane & 15;
  int koff = ((lane >> 4) << 4) ^ (((rsel >> 1) & 3) << 4);
  int wm = (w >> 2) * 64, wn = (w & 3) * 64;

  // XCD-contiguous, n-fast within groups of 4 bm (A window ~1MB L2-resident)
  int bid = blockIdx.x;
  int xcd = bid & 7;
  int loc = bid >> 3;             // [0, 512)
  int g = loc >> 8;               // {0,1}
  int i5 = loc & 255;
  int bn = i5 >> 2;               // [0,64)
  int bm = xcd * 8 + g * 4 + (i5 & 3);
  long long m0 = (long long)bm * 128;
  int n0 = bn * 128;

  // staging source (pre-swizzled column = involution of read swizzle)
  int cidA = w * 64 + lane;                 // [0,512)
  int rA = cidA >> 2;
  int cA = ((cidA & 3) ^ ((rA >> 1) & 3)) << 4;
  int cidB0 = w * 128 + lane, cidB1 = cidB0 + 64;   // [0,1024)
  int rB0 = cidB0 >> 2, rB1 = cidB1 >> 2;
  int cB0 = ((cidB0 & 3) ^ ((rB0 >> 1) & 3)) << 4;
  int cB1 = ((cidB1 & 3) ^ ((rB1 >> 1) & 3)) << 4;
  const uint8_t* srcA = A + (m0 + rA) * (long long)DMODEL + cA;
  long long gr0 = (rB0 < 128) ? (long long)(n0 + rB0) : (long long)(HID + n0 + rB0 - 128);
  long long gr1 = (rB1 < 128) ? (long long)(n0 + rB1) : (long long)(HID + n0 + rB1 - 128);
  const uint8_t* srcB0 = Bq + gr0 * DMODEL + cB0;
  const uint8_t* srcB1 = Bq + gr1 * DMODEL + cB1;

  v4i acc[4][4] = {};
  kloop<DMODEL / 64>(srcA, srcB0, srcB1, smem, w, rsel, koff, wm, wn, acc);

  __syncthreads();   // all waves done with K-loop LDS before reuse as sil buffer

  // ---- epilogue: gate waves (wn>=128) publish silu via LDS; value waves write H2 ----
  float sgv = scales[0];
  int q4 = (lane >> 4) << 2;
  float* sil = (float*)smem;      // [128 tokens][132]
  if (wn >= 128) {
#pragma unroll
    for (int i = 0; i < 4; ++i) {
#pragma unroll
      for (int r = 0; r < 4; ++r) {
        int ri = wm + i * 16 + q4 + r;
        float ds = d1[m0 + ri] * sgv;
#pragma unroll
        for (int j = 0; j < 4; ++j) {
          float gg = (float)acc[i][j][r] * ds;
          sil[ri * 132 + (wn - 128) + j * 16 + rsel] = gg / (1.0f + expf(-gg));
        }
      }
    }
  }
  __syncthreads();
  if (wn < 128) {
#pragma unroll
    for (int i = 0; i < 4; ++i) {
#pragma unroll
      for (int r = 0; r < 4; ++r) {
        int ri = wm + i * 16 + q4 + r;
        long long token = m0 + ri;
        float ds = d1[token] * sgv;
        float* hrow = H2 + token * HID + n0;
#pragma unroll
        for (int j = 0; j < 4; ++j) {
          float v = (float)acc[i][j][r] * ds;
          hrow[wn + j * 16 + rsel] = v * sil[ri * 132 + wn + j * 16 + rsel];
        }
      }
    }
  }
}

// ---------------- per-token int8 quant of h2 (row of 8192) ----------------
__global__ __launch_bounds__(256) void k_hquant(const float* __restrict__ H2,
                                                uint8_t* __restrict__ A2,
                                                float* __restrict__ d2) {
  int t = blockIdx.x;
  int tid = threadIdx.x;
  const float4* hr = (const float4*)(H2 + (long long)t * HID);
  float4 v[8];
  float am = 0.f;
  for (int p = 0; p < 8; p++) {
    v[p] = hr[tid + p * 256];
    am = fmaxf(am, fmaxf(fmaxf(fabsf(v[p].x), fabsf(v[p].y)), fmaxf(fabsf(v[p].z), fabsf(v[p].w))));
  }
  int lane = tid & 63, wave = tid >> 6;
  for (int off = 32; off > 0; off >>= 1) am = fmaxf(am, __shfl_down(am, off));
  __shared__ float wmax[4];
  if (lane == 0) wmax[wave] = am;
  __syncthreads();
  float amc = fmaxf(fmaxf(fmaxf(wmax[0], wmax[1]), fmaxf(wmax[2], wmax[3])), 1e-5f);
  float scale = 127.0f / amc;
  uint32_t* arow = (uint32_t*)(A2 + (long long)t * HID);
  for (int p = 0; p < 8; p++) {
    int q0 = q127(v[p].x * scale);
    int q1 = q127(v[p].y * scale);
    int q2 = q127(v[p].z * scale);
    int q3 = q127(v[p].w * scale);
    arow[tid + p * 256] = (uint32_t)(q0 & 0xff) | ((uint32_t)(q1 & 0xff) << 8) |
                          ((uint32_t)(q2 & 0xff) << 16) | ((uint32_t)(q3 & 0xff) << 24);
  }
  if (tid == 0) d2[t] = amc / 127.0f;
}

// ---------------- GEMM2: 128 tokens x 256 d_model cols + residual ----------------
__global__ __launch_bounds__(512, 4) void k_gemm2_v4(
    const uint8_t* __restrict__ A2, const uint8_t* __restrict__ Bq,
    const float* __restrict__ d2, const float* __restrict__ scales,
    const float* __restrict__ x, float* __restrict__ out) {
  __shared__ __align__(16) uint8_t smem[3 * TILE_B];
  int tid = threadIdx.x, lane = tid & 63, w = tid >> 6;
  int rsel = lane & 15;
  int koff = ((lane >> 4) << 4) ^ (((rsel >> 1) & 3) << 4);
  int wm = (w >> 2) * 64, wn = (w & 3) * 64;

  // grid 64 x 8 = 512; per XCD 8bm x 8bn, groups of 2 bm (A window 2MB)
  int bid = blockIdx.x;
  int xcd = bid & 7;
  int loc = bid >> 3;             // [0,64)
  int g = loc >> 4;               // [0,4)
  int i5 = loc & 15;
  int bn = i5 >> 1;               // [0,8)
  int bm = xcd * 8 + g * 2 + (i5 & 1);
  long long m0 = (long long)bm * 128;
  int n0 = bn * 256;

  int cidA = w * 64 + lane;
  int rA = cidA >> 2;
  int cA = ((cidA & 3) ^ ((rA >> 1) & 3)) << 4;
  int cidB0 = w * 128 + lane, cidB1 = cidB0 + 64;
  int rB0 = cidB0 >> 2, rB1 = cidB1 >> 2;
  int cB0 = ((cidB0 & 3) ^ ((rB0 >> 1) & 3)) << 4;
  int cB1 = ((cidB1 & 3) ^ ((rB1 >> 1) & 3)) << 4;
  const uint8_t* srcA = A2 + (m0 + rA) * (long long)HID + cA;
  const uint8_t* srcB0 = Bq + (long long)(n0 + rB0) * HID + cB0;
  const uint8_t* srcB1 = Bq + (long long)(n0 + rB1) * HID + cB1;

  v4i acc[4][4] = {};
  kloop<HID / 64>(srcA, srcB0, srcB1, smem, w, rsel, koff, wm, wn, acc);

  float so = scales[1];
  int q4 = (lane >> 4) << 2;
#pragma unroll
  for (int i = 0; i < 4; ++i) {
#pragma unroll
    for (int r = 0; r < 4; ++r) {
      long long token = m0 + wm + i * 16 + q4 + r;
      float ds = d2[token] * so;
      const float* xr = x + token * DMODEL;
      float* orow = out + token * DMODEL;
#pragma unroll
      for (int j = 0; j < 4; ++j) {
        int c = n0 + wn + j * 16 + rsel;
        orow[c] = xr[c] + (float)acc[i][j][r] * ds;
      }
    }
  }
}

extern "C" void kernel_launch(void* const* d_in, const int* in_sizes, int n_in,
                              void* d_out, int out_size, void* d_ws, size_t ws_size,
                              hipStream_t stream) {
  const float* x      = (const float*)d_in[0];
  const float* norm_w = (const float*)d_in[1];
  const float* w_gv   = (const float*)d_in[2];
  const float* w_out  = (const float*)d_in[3];
  float* out = (float*)d_out;

  char* ws = (char*)d_ws;
  size_t off = 0;
  float*   H2    = (float*)(ws + off);   off += (size_t)TOKENS * HID * 4;   // 268 MB
  uint8_t* A2    = (uint8_t*)(ws + off); off += (size_t)TOKENS * HID;       // 67 MB
  uint8_t* Wqgv  = (uint8_t*)(ws + off); off += (size_t)2 * HID * DMODEL;   // 33.5 MB
  uint8_t* Wqout = (uint8_t*)(ws + off); off += (size_t)DMODEL * HID;       // 16.8 MB
  uint8_t* A1    = (uint8_t*)(ws + off); off += (size_t)TOKENS * DMODEL;    // 16.8 MB
  float*   d1    = (float*)(ws + off);   off += (size_t)TOKENS * 4;
  float*   d2    = (float*)(ws + off);   off += (size_t)TOKENS * 4;
  double*  pgv   = (double*)(ws + off);  off += 1024 * 8;
  double*  pout  = (double*)(ws + off);  off += 512 * 8;
  float*   scales = (float*)(ws + off);  off += 16;

  const long long ngv = (long long)2 * HID * DMODEL;   // 33554432
  const long long nout = (long long)DMODEL * HID;      // 16777216

  k_abssum<<<1024, 256, 0, stream>>>(w_gv, ngv / 4, pgv);
  k_abssum<<<512, 256, 0, stream>>>(w_out, nout / 4, pout);
  k_finalize<<<1, 256, 0, stream>>>(pgv, 1024, (double)ngv, pout, 512, (double)nout, scales);
  k_wquant<<<(int)((ngv / 4 + 255) / 256), 256, 0, stream>>>(w_gv, ngv / 4, scales + 0, Wqgv);
  k_wquant<<<(int)((nout / 4 + 255) / 256), 256, 0, stream>>>(w_out, nout / 4, scales + 1, Wqout);
  k_rmsnorm_quant<<<TOKENS, 256, 0, stream>>>(x, norm_w, A1, d1);
  k_gemm1_v4<<<dim3((TOKENS / 128) * (HID / 128)), 512, 0, stream>>>(A1, Wqgv, d1, scales, H2);
  k_hquant<<<TOKENS, 256, 0, stream>>>(H2, A2, d2);
  k_gemm2_v4<<<dim3((TOKENS / 128) * (DMODEL / 256)), 512, 0, stream>>>(A2, Wqout, d2, scales, x, out);
}

// Round 5
// 819.469 us; speedup vs baseline: 1.2499x; 1.0226x over previous
//
#include <hip/hip_runtime.h>
#include <stdint.h>
#include <math.h>

#define TOKENS 8192
#define DMODEL 2048
#define HID    8192

// Block tile: 128 tokens (BM) x 256 B-rows (BR), BK=64 bytes.
// 8 waves (2M x 4N), wave tile 64x64, acc[4][4] = 64 AGPR -> <=128 regs/thread.
// 3-deep LDS pipeline (3 x 24KB = 72KB) -> 2 blocks/CU (16 waves), counted vmcnt.
#define TILE_B 24576

typedef __attribute__((ext_vector_type(4))) int v4i;

typedef const __attribute__((address_space(1))) uint32_t gu32;
typedef __attribute__((address_space(3))) uint32_t lu32;

__device__ __forceinline__ void gload16(const void* g, void* l) {
  // async global->LDS DMA; dest = wave-uniform base + lane*16
  __builtin_amdgcn_global_load_lds((gu32*)g, (lu32*)l, 16, 0, 0);
}

// ---------------- weight absmean: partial |w| sums (fp64) ----------------
__global__ __launch_bounds__(256) void k_abssum(const float* __restrict__ w, long long n4,
                                                double* __restrict__ partial) {
  long long i0 = (long long)blockIdx.x * 256 + threadIdx.x;
  long long stride = (long long)gridDim.x * 256;
  const float4* w4 = (const float4*)w;
  double s = 0.0;
  for (long long i = i0; i < n4; i += stride) {
    float4 v = w4[i];
    s += (double)fabsf(v.x) + (double)fabsf(v.y) + (double)fabsf(v.z) + (double)fabsf(v.w);
  }
  __shared__ double sm[256];
  sm[threadIdx.x] = s;
  __syncthreads();
  for (int off = 128; off > 0; off >>= 1) {
    if ((int)threadIdx.x < off) sm[threadIdx.x] += sm[threadIdx.x + off];
    __syncthreads();
  }
  if (threadIdx.x == 0) partial[blockIdx.x] = sm[0];
}

// ---------------- finalize: s = max(mean|w|, 1e-5) for both weights ----------------
__global__ __launch_bounds__(256) void k_finalize(const double* __restrict__ pg, int ng, double cg,
                                                  const double* __restrict__ po, int no, double co,
                                                  float* __restrict__ scales) {
  __shared__ double sm[256];
  int tid = threadIdx.x;
  double s = 0.0;
  for (int i = tid; i < ng; i += 256) s += pg[i];
  sm[tid] = s; __syncthreads();
  for (int off = 128; off > 0; off >>= 1) { if (tid < off) sm[tid] += sm[tid + off]; __syncthreads(); }
  if (tid == 0) scales[0] = (float)fmax(sm[0] / cg, 1e-5);
  __syncthreads();
  s = 0.0;
  for (int i = tid; i < no; i += 256) s += po[i];
  sm[tid] = s; __syncthreads();
  for (int off = 128; off > 0; off >>= 1) { if (tid < off) sm[tid] += sm[tid + off]; __syncthreads(); }
  if (tid == 0) scales[1] = (float)fmax(sm[0] / co, 1e-5);
}

// ---------------- ternary weight quant: q = clip(rint(w/s), -1, 1) ----------------
__global__ __launch_bounds__(256) void k_wquant(const float* __restrict__ w, long long n4,
                                                const float* __restrict__ sptr,
                                                uint8_t* __restrict__ q) {
  long long i = (long long)blockIdx.x * 256 + threadIdx.x;
  if (i >= n4) return;
  float s = *sptr;
  float4 v = ((const float4*)w)[i];
  int q0 = (int)rintf(v.x / s); q0 = q0 < -1 ? -1 : (q0 > 1 ? 1 : q0);
  int q1 = (int)rintf(v.y / s); q1 = q1 < -1 ? -1 : (q1 > 1 ? 1 : q1);
  int q2 = (int)rintf(v.z / s); q2 = q2 < -1 ? -1 : (q2 > 1 ? 1 : q2);
  int q3 = (int)rintf(v.w / s); q3 = q3 < -1 ? -1 : (q3 > 1 ? 1 : q3);
  uint32_t packed = (uint32_t)(q0 & 0xff) | ((uint32_t)(q1 & 0xff) << 8) |
                    ((uint32_t)(q2 & 0xff) << 16) | ((uint32_t)(q3 & 0xff) << 24);
  ((uint32_t*)q)[i] = packed;
}

__device__ __forceinline__ int q127(float a) {
  float r = rintf(a);
  r = fminf(fmaxf(r, -127.0f), 127.0f);
  return (int)r;
}

// ---------------- fused RMSNorm + per-token int8 quant ----------------
__global__ __launch_bounds__(256) void k_rmsnorm_quant(const float* __restrict__ x,
                                                       const float* __restrict__ g,
                                                       uint8_t* __restrict__ a1,
                                                       float* __restrict__ d1) {
  int t = blockIdx.x;
  int tid = threadIdx.x;
  const float4* xr = (const float4*)(x + (long long)t * DMODEL);
  const float4* gr = (const float4*)g;
  float4 xv[2], gv[2];
  xv[0] = xr[tid]; xv[1] = xr[tid + 256];
  gv[0] = gr[tid]; gv[1] = gr[tid + 256];
  double ss = 0.0;
  for (int p = 0; p < 2; p++) {
    float4 v = xv[p];
    ss += (double)v.x * v.x + (double)v.y * v.y + (double)v.z * v.z + (double)v.w * v.w;
  }
  int lane = tid & 63, wave = tid >> 6;
  for (int off = 32; off > 0; off >>= 1) ss += __shfl_down(ss, off);
  __shared__ double wsum[4];
  if (lane == 0) wsum[wave] = ss;
  __syncthreads();
  double var = (wsum[0] + wsum[1] + wsum[2] + wsum[3]) / (double)DMODEL;
  float r = (float)(1.0 / sqrt(var + 1e-5));
  float h[8];
  h[0] = xv[0].x * r * gv[0].x; h[1] = xv[0].y * r * gv[0].y;
  h[2] = xv[0].z * r * gv[0].z; h[3] = xv[0].w * r * gv[0].w;
  h[4] = xv[1].x * r * gv[1].x; h[5] = xv[1].y * r * gv[1].y;
  h[6] = xv[1].z * r * gv[1].z; h[7] = xv[1].w * r * gv[1].w;
  float am = 0.f;
  for (int k = 0; k < 8; k++) am = fmaxf(am, fabsf(h[k]));
  for (int off = 32; off > 0; off >>= 1) am = fmaxf(am, __shfl_down(am, off));
  __shared__ float wmax[4];
  if (lane == 0) wmax[wave] = am;
  __syncthreads();
  float amc = fmaxf(fmaxf(fmaxf(wmax[0], wmax[1]), fmaxf(wmax[2], wmax[3])), 1e-5f);
  float scale = 127.0f / amc;
  uint32_t* arow = (uint32_t*)(a1 + (long long)t * DMODEL);
  for (int p = 0; p < 2; p++) {
    int q0 = q127(h[p * 4 + 0] * scale);
    int q1 = q127(h[p * 4 + 1] * scale);
    int q2 = q127(h[p * 4 + 2] * scale);
    int q3 = q127(h[p * 4 + 3] * scale);
    arow[tid + p * 256] = (uint32_t)(q0 & 0xff) | ((uint32_t)(q1 & 0xff) << 8) |
                          ((uint32_t)(q2 & 0xff) << 16) | ((uint32_t)(q3 & 0xff) << 24);
  }
  if (tid == 0) d1[t] = amc / 127.0f;
}

// ================= shared K-loop: 3-deep pipeline, counted vmcnt =================
// Per tile: issue stage(t+2); ds_read frags (ordered first-use-first) interleaved by the
// COMPILER with the 16 MFMAs (fine-grained lgkmcnt — no forced drain, no order pinning);
// vmcnt(3); barrier. vmcnt(3) leaves t+2's loads in flight (never drain in steady state).
// Read order af0,bf0..bf3,af1..af3 lets the first MFMA start after 2 reads complete.
template<int NT>
__device__ __forceinline__ void kloop(const uint8_t* srcA, const uint8_t* srcB0,
                                      const uint8_t* srcB1, uint8_t* smem,
                                      int w, int rsel, int koff, int wm, int wn,
                                      v4i (&acc)[4][4]) {
  int ldsA = w * 1024;
  int ldsB = 8192 + w * 2048;
  // prologue: stage tiles 0 and 1
  gload16(srcA,       smem + ldsA);
  gload16(srcB0,      smem + ldsB);
  gload16(srcB1,      smem + ldsB + 1024);
  gload16(srcA + 64,  smem + TILE_B + ldsA);
  gload16(srcB0 + 64, smem + TILE_B + ldsB);
  gload16(srcB1 + 64, smem + TILE_B + ldsB + 1024);
  asm volatile("s_waitcnt vmcnt(3)" ::: "memory");   // tile 0 resident, tile 1 in flight
  __builtin_amdgcn_sched_barrier(0);
  __builtin_amdgcn_s_barrier();

  int cur = 0, nxt = 2 * TILE_B;
#pragma unroll 3
  for (int t = 0; t < NT; ++t) {
    if (t + 2 < NT) {
      int ko = (t + 2) * 64;
      gload16(srcA + ko,  smem + nxt + ldsA);
      gload16(srcB0 + ko, smem + nxt + ldsB);
      gload16(srcB1 + ko, smem + nxt + ldsB + 1024);
    }
    __builtin_amdgcn_sched_barrier(0);   // pin: prefetch issued before compute region
    const uint8_t* bA = smem + cur;
    const uint8_t* bB = bA + 8192;
    __builtin_amdgcn_s_setprio(1);
    // reads in first-use order; compiler interleaves MFMAs with counted lgkm waits
    v4i af0 = *(const v4i*)(bA + (wm + 0 * 16 + rsel) * 64 + koff);
    v4i bf0 = *(const v4i*)(bB + (wn + 0 * 16 + rsel) * 64 + koff);
    v4i bf1 = *(const v4i*)(bB + (wn + 1 * 16 + rsel) * 64 + koff);
    v4i bf2 = *(const v4i*)(bB + (wn + 2 * 16 + rsel) * 64 + koff);
    v4i bf3 = *(const v4i*)(bB + (wn + 3 * 16 + rsel) * 64 + koff);
    v4i af1 = *(const v4i*)(bA + (wm + 1 * 16 + rsel) * 64 + koff);
    v4i af2 = *(const v4i*)(bA + (wm + 2 * 16 + rsel) * 64 + koff);
    v4i af3 = *(const v4i*)(bA + (wm + 3 * 16 + rsel) * 64 + koff);
    acc[0][0] = __builtin_amdgcn_mfma_i32_16x16x64_i8(af0, bf0, acc[0][0], 0, 0, 0);
    acc[0][1] = __builtin_amdgcn_mfma_i32_16x16x64_i8(af0, bf1, acc[0][1], 0, 0, 0);
    acc[0][2] = __builtin_amdgcn_mfma_i32_16x16x64_i8(af0, bf2, acc[0][2], 0, 0, 0);
    acc[0][3] = __builtin_amdgcn_mfma_i32_16x16x64_i8(af0, bf3, acc[0][3], 0, 0, 0);
    acc[1][0] = __builtin_amdgcn_mfma_i32_16x16x64_i8(af1, bf0, acc[1][0], 0, 0, 0);
    acc[1][1] = __builtin_amdgcn_mfma_i32_16x16x64_i8(af1, bf1, acc[1][1], 0, 0, 0);
    acc[1][2] = __builtin_amdgcn_mfma_i32_16x16x64_i8(af1, bf2, acc[1][2], 0, 0, 0);
    acc[1][3] = __builtin_amdgcn_mfma_i32_16x16x64_i8(af1, bf3, acc[1][3], 0, 0, 0);
    acc[2][0] = __builtin_amdgcn_mfma_i32_16x16x64_i8(af2, bf0, acc[2][0], 0, 0, 0);
    acc[2][1] = __builtin_amdgcn_mfma_i32_16x16x64_i8(af2, bf1, acc[2][1], 0, 0, 0);
    acc[2][2] = __builtin_amdgcn_mfma_i32_16x16x64_i8(af2, bf2, acc[2][2], 0, 0, 0);
    acc[2][3] = __builtin_amdgcn_mfma_i32_16x16x64_i8(af2, bf3, acc[2][3], 0, 0, 0);
    acc[3][0] = __builtin_amdgcn_mfma_i32_16x16x64_i8(af3, bf0, acc[3][0], 0, 0, 0);
    acc[3][1] = __builtin_amdgcn_mfma_i32_16x16x64_i8(af3, bf1, acc[3][1], 0, 0, 0);
    acc[3][2] = __builtin_amdgcn_mfma_i32_16x16x64_i8(af3, bf2, acc[3][2], 0, 0, 0);
    acc[3][3] = __builtin_amdgcn_mfma_i32_16x16x64_i8(af3, bf3, acc[3][3], 0, 0, 0);
    __builtin_amdgcn_s_setprio(0);
    if (t < NT - 1) {
      if (t + 2 < NT) asm volatile("s_waitcnt vmcnt(3)" ::: "memory");  // t+1 resident
      else            asm volatile("s_waitcnt vmcnt(0)" ::: "memory");  // drain tail
      __builtin_amdgcn_sched_barrier(0);
      __builtin_amdgcn_s_barrier();
    }
    cur += TILE_B; if (cur == 3 * TILE_B) cur = 0;
    nxt += TILE_B; if (nxt == 3 * TILE_B) nxt = 0;
  }
}

// ---------------- GEMM1: 128 tokens x 128 out-cols (64v+64g per N-wave pair), fused SwiGLU ----------------
__global__ __launch_bounds__(512, 4) void k_gemm1_v5(
    const uint8_t* __restrict__ A, const uint8_t* __restrict__ Bq,
    const float* __restrict__ d1, const float* __restrict__ scales,
    float* __restrict__ H2) {
  __shared__ __align__(16) uint8_t smem[3 * TILE_B];   // 72KB >= epilogue 128*132*4
  int tid = threadIdx.x, lane = tid & 63, w = tid >> 6;
  int rsel = lane & 15;
  int koff = ((lane >> 4) << 4) ^ (((rsel >> 1) & 3) << 4);
  int wm = (w >> 2) * 64, wn = (w & 3) * 64;

  // XCD-contiguous, n-fast within groups of 4 bm (A window ~1MB L2-resident)
  int bid = blockIdx.x;
  int xcd = bid & 7;
  int loc = bid >> 3;             // [0, 512)
  int g = loc >> 8;               // {0,1}
  int i5 = loc & 255;
  int bn = i5 >> 2;               // [0,64)
  int bm = xcd * 8 + g * 4 + (i5 & 3);
  long long m0 = (long long)bm * 128;
  int n0 = bn * 128;

  // staging source (pre-swizzled column = involution of read swizzle)
  int cidA = w * 64 + lane;                 // [0,512)
  int rA = cidA >> 2;
  int cA = ((cidA & 3) ^ ((rA >> 1) & 3)) << 4;
  int cidB0 = w * 128 + lane, cidB1 = cidB0 + 64;   // [0,1024)
  int rB0 = cidB0 >> 2, rB1 = cidB1 >> 2;
  int cB0 = ((cidB0 & 3) ^ ((rB0 >> 1) & 3)) << 4;
  int cB1 = ((cidB1 & 3) ^ ((rB1 >> 1) & 3)) << 4;
  const uint8_t* srcA = A + (m0 + rA) * (long long)DMODEL + cA;
  long long gr0 = (rB0 < 128) ? (long long)(n0 + rB0) : (long long)(HID + n0 + rB0 - 128);
  long long gr1 = (rB1 < 128) ? (long long)(n0 + rB1) : (long long)(HID + n0 + rB1 - 128);
  const uint8_t* srcB0 = Bq + gr0 * DMODEL + cB0;
  const uint8_t* srcB1 = Bq + gr1 * DMODEL + cB1;

  v4i acc[4][4] = {};
  kloop<DMODEL / 64>(srcA, srcB0, srcB1, smem, w, rsel, koff, wm, wn, acc);

  __syncthreads();   // all waves done with K-loop LDS before reuse as sil buffer

  // ---- epilogue: gate waves (wn>=128) publish silu via LDS; value waves write H2 ----
  float sgv = scales[0];
  int q4 = (lane >> 4) << 2;
  float* sil = (float*)smem;      // [128 tokens][132]
  if (wn >= 128) {
#pragma unroll
    for (int i = 0; i < 4; ++i) {
#pragma unroll
      for (int r = 0; r < 4; ++r) {
        int ri = wm + i * 16 + q4 + r;
        float ds = d1[m0 + ri] * sgv;
#pragma unroll
        for (int j = 0; j < 4; ++j) {
          float gg = (float)acc[i][j][r] * ds;
          sil[ri * 132 + (wn - 128) + j * 16 + rsel] = gg / (1.0f + expf(-gg));
        }
      }
    }
  }
  __syncthreads();
  if (wn < 128) {
#pragma unroll
    for (int i = 0; i < 4; ++i) {
#pragma unroll
      for (int r = 0; r < 4; ++r) {
        int ri = wm + i * 16 + q4 + r;
        long long token = m0 + ri;
        float ds = d1[token] * sgv;
        float* hrow = H2 + token * HID + n0;
#pragma unroll
        for (int j = 0; j < 4; ++j) {
          float v = (float)acc[i][j][r] * ds;
          hrow[wn + j * 16 + rsel] = v * sil[ri * 132 + wn + j * 16 + rsel];
        }
      }
    }
  }
}

// ---------------- per-token int8 quant of h2 (row of 8192) ----------------
__global__ __launch_bounds__(256) void k_hquant(const float* __restrict__ H2,
                                                uint8_t* __restrict__ A2,
                                                float* __restrict__ d2) {
  int t = blockIdx.x;
  int tid = threadIdx.x;
  const float4* hr = (const float4*)(H2 + (long long)t * HID);
  float4 v[8];
  float am = 0.f;
  for (int p = 0; p < 8; p++) {
    v[p] = hr[tid + p * 256];
    am = fmaxf(am, fmaxf(fmaxf(fabsf(v[p].x), fabsf(v[p].y)), fmaxf(fabsf(v[p].z), fabsf(v[p].w))));
  }
  int lane = tid & 63, wave = tid >> 6;
  for (int off = 32; off > 0; off >>= 1) am = fmaxf(am, __shfl_down(am, off));
  __shared__ float wmax[4];
  if (lane == 0) wmax[wave] = am;
  __syncthreads();
  float amc = fmaxf(fmaxf(fmaxf(wmax[0], wmax[1]), fmaxf(wmax[2], wmax[3])), 1e-5f);
  float scale = 127.0f / amc;
  uint32_t* arow = (uint32_t*)(A2 + (long long)t * HID);
  for (int p = 0; p < 8; p++) {
    int q0 = q127(v[p].x * scale);
    int q1 = q127(v[p].y * scale);
    int q2 = q127(v[p].z * scale);
    int q3 = q127(v[p].w * scale);
    arow[tid + p * 256] = (uint32_t)(q0 & 0xff) | ((uint32_t)(q1 & 0xff) << 8) |
                          ((uint32_t)(q2 & 0xff) << 16) | ((uint32_t)(q3 & 0xff) << 24);
  }
  if (tid == 0) d2[t] = amc / 127.0f;
}

// ---------------- GEMM2: 128 tokens x 256 d_model cols + residual ----------------
__global__ __launch_bounds__(512, 4) void k_gemm2_v5(
    const uint8_t* __restrict__ A2, const uint8_t* __restrict__ Bq,
    const float* __restrict__ d2, const float* __restrict__ scales,
    const float* __restrict__ x, float* __restrict__ out) {
  __shared__ __align__(16) uint8_t smem[3 * TILE_B];
  int tid = threadIdx.x, lane = tid & 63, w = tid >> 6;
  int rsel = lane & 15;
  int koff = ((lane >> 4) << 4) ^ (((rsel >> 1) & 3) << 4);
  int wm = (w >> 2) * 64, wn = (w & 3) * 64;

  // grid 64 x 8 = 512; per XCD 8bm x 8bn, groups of 2 bm (A window 2MB)
  int bid = blockIdx.x;
  int xcd = bid & 7;
  int loc = bid >> 3;             // [0,64)
  int g = loc >> 4;               // [0,4)
  int i5 = loc & 15;
  int bn = i5 >> 1;               // [0,8)
  int bm = xcd * 8 + g * 2 + (i5 & 1);
  long long m0 = (long long)bm * 128;
  int n0 = bn * 256;

  int cidA = w * 64 + lane;
  int rA = cidA >> 2;
  int cA = ((cidA & 3) ^ ((rA >> 1) & 3)) << 4;
  int cidB0 = w * 128 + lane, cidB1 = cidB0 + 64;
  int rB0 = cidB0 >> 2, rB1 = cidB1 >> 2;
  int cB0 = ((cidB0 & 3) ^ ((rB0 >> 1) & 3)) << 4;
  int cB1 = ((cidB1 & 3) ^ ((rB1 >> 1) & 3)) << 4;
  const uint8_t* srcA = A2 + (m0 + rA) * (long long)HID + cA;
  const uint8_t* srcB0 = Bq + (long long)(n0 + rB0) * HID + cB0;
  const uint8_t* srcB1 = Bq + (long long)(n0 + rB1) * HID + cB1;

  v4i acc[4][4] = {};
  kloop<HID / 64>(srcA, srcB0, srcB1, smem, w, rsel, koff, wm, wn, acc);

  float so = scales[1];
  int q4 = (lane >> 4) << 2;
#pragma unroll
  for (int i = 0; i < 4; ++i) {
#pragma unroll
    for (int r = 0; r < 4; ++r) {
      long long token = m0 + wm + i * 16 + q4 + r;
      float ds = d2[token] * so;
      const float* xr = x + token * DMODEL;
      float* orow = out + token * DMODEL;
#pragma unroll
      for (int j = 0; j < 4; ++j) {
        int c = n0 + wn + j * 16 + rsel;
        orow[c] = xr[c] + (float)acc[i][j][r] * ds;
      }
    }
  }
}

extern "C" void kernel_launch(void* const* d_in, const int* in_sizes, int n_in,
                              void* d_out, int out_size, void* d_ws, size_t ws_size,
                              hipStream_t stream) {
  const float* x      = (const float*)d_in[0];
  const float* norm_w = (const float*)d_in[1];
  const float* w_gv   = (const float*)d_in[2];
  const float* w_out  = (const float*)d_in[3];
  float* out = (float*)d_out;

  char* ws = (char*)d_ws;
  size_t off = 0;
  float*   H2    = (float*)(ws + off);   off += (size_t)TOKENS * HID * 4;   // 268 MB
  uint8_t* A2    = (uint8_t*)(ws + off); off += (size_t)TOKENS * HID;       // 67 MB
  uint8_t* Wqgv  = (uint8_t*)(ws + off); off += (size_t)2 * HID * DMODEL;   // 33.5 MB
  uint8_t* Wqout = (uint8_t*)(ws + off); off += (size_t)DMODEL * HID;       // 16.8 MB
  uint8_t* A1    = (uint8_t*)(ws + off); off += (size_t)TOKENS * DMODEL;    // 16.8 MB
  float*   d1    = (float*)(ws + off);   off += (size_t)TOKENS * 4;
  float*   d2    = (float*)(ws + off);   off += (size_t)TOKENS * 4;
  double*  pgv   = (double*)(ws + off);  off += 1024 * 8;
  double*  pout  = (double*)(ws + off);  off += 512 * 8;
  float*   scales = (float*)(ws + off);  off += 16;

  const long long ngv = (long long)2 * HID * DMODEL;   // 33554432
  const long long nout = (long long)DMODEL * HID;      // 16777216

  k_abssum<<<1024, 256, 0, stream>>>(w_gv, ngv / 4, pgv);
  k_abssum<<<512, 256, 0, stream>>>(w_out, nout / 4, pout);
  k_finalize<<<1, 256, 0, stream>>>(pgv, 1024, (double)ngv, pout, 512, (double)nout, scales);
  k_wquant<<<(int)((ngv / 4 + 255) / 256), 256, 0, stream>>>(w_gv, ngv / 4, scales + 0, Wqgv);
  k_wquant<<<(int)((nout / 4 + 255) / 256), 256, 0, stream>>>(w_out, nout / 4, scales + 1, Wqout);
  k_rmsnorm_quant<<<TOKENS, 256, 0, stream>>>(x, norm_w, A1, d1);
  k_gemm1_v5<<<dim3((TOKENS / 128) * (HID / 128)), 512, 0, stream>>>(A1, Wqgv, d1, scales, H2);
  k_hquant<<<TOKENS, 256, 0, stream>>>(H2, A2, d2);
  k_gemm2_v5<<<dim3((TOKENS / 128) * (DMODEL / 256)), 512, 0, stream>>>(A2, Wqout, d2, scales, x, out);
}